// Round 8
// baseline (3079.848 us; speedup 1.0000x reference)
//
#include <hip/hip_runtime.h>

// Problem dims (fp32 in / fp32 out)
#define B_   64
#define T_   512
#define DIN_ 256
#define H_   512
#define DOUT_ 128

typedef _Float16 f16x8 __attribute__((ext_vector_type(8)));
typedef float f32x4  __attribute__((ext_vector_type(4)));
typedef float f32x2  __attribute__((ext_vector_type(2)));
typedef _Float16 half2v __attribute__((ext_vector_type(2)));

// ---------------------------------------------------------------------------
// dot of 8 f16 pairs (w,h packed as uint4) accumulated into fp32
__device__ __forceinline__ float dot8(uint4 w, uint4 h, float s) {
#if __has_builtin(__builtin_amdgcn_fdot2)
  s = __builtin_amdgcn_fdot2(__builtin_bit_cast(half2v, w.x), __builtin_bit_cast(half2v, h.x), s, false);
  s = __builtin_amdgcn_fdot2(__builtin_bit_cast(half2v, w.y), __builtin_bit_cast(half2v, h.y), s, false);
  s = __builtin_amdgcn_fdot2(__builtin_bit_cast(half2v, w.z), __builtin_bit_cast(half2v, h.z), s, false);
  s = __builtin_amdgcn_fdot2(__builtin_bit_cast(half2v, w.w), __builtin_bit_cast(half2v, h.w), s, false);
#else
  const half2v* wp = (const half2v*)&w;
  const half2v* hp = (const half2v*)&h;
#pragma unroll
  for (int q = 0; q < 4; ++q) {
    s += (float)wp[q][0] * (float)hp[q][0] + (float)wp[q][1] * (float)hp[q][1];
  }
#endif
  return s;
}

// fast branchless tanh: tanh(x) = sign(x) * (1 - 2/(e^{2|x|}+1)); |err| ~1e-6
__device__ __forceinline__ float fast_tanh(float x) {
  float a = fabsf(x);
  float e = __expf(2.f * a);
  float r = 1.f - 2.f / (e + 1.f);
  return copysignf(r, x);
}

// opaque pin: keep v in arch VGPRs, producing loads non-rematerializable
__device__ __forceinline__ void pin4(uint4& v) {
  asm volatile("" : "+v"(v.x), "+v"(v.y), "+v"(v.z), "+v"(v.w));
}

// ---------------------------------------------------------------------------
// Generic fp32 -> f16 conversion (memory-bound, one-shot prep)
__global__ void cvt_f32_f16(const float* __restrict__ in, _Float16* __restrict__ out, int n) {
  int idx = blockIdx.x * 256 + threadIdx.x;
  if (idx < n) out[idx] = (_Float16)in[idx];
}

// ---------------------------------------------------------------------------
// Prep: W_hh (fp32 HxH) -> scan layout for the 1024-thread scan:
//   chunk c = s*1024 + tid  holds  W[2*(tid&255) + (s>>4)][kc*8 .. kc*8+8)
//   with kc = (tid>>8)*16 + (s&15).
// (tid = scan thread, s = slot 0..31: 0..15 even row chunks, 16..31 odd row.)
// Scan loads slot s at lane-stride 16 B -> fully coalesced.
__global__ void prep_w(const float* __restrict__ w0, const float* __restrict__ w1,
                       _Float16* __restrict__ o0, _Float16* __restrict__ o1) {
  int idx = blockIdx.x * 256 + threadIdx.x;        // 0 .. 65535 (two matrices)
  const float* src = (idx < 32768) ? w0 : w1;
  _Float16* dst = (idx < 32768) ? o0 : o1;
  int c = idx & 32767;
  int tid = c & 1023;
  int s   = c >> 10;          // 0..31
  int row = 2 * (tid & 255) + (s >> 4);
  int kc  = (tid >> 8) * 16 + (s & 15);
#pragma unroll
  for (int e = 0; e < 8; ++e)
    dst[(size_t)c * 8 + e] = (_Float16)src[row * 512 + kc * 8 + e];
}

// ---------------------------------------------------------------------------
// GEMM: out[m,n] = sum_k X[m,k]*W[n,k] + bias1[n] + bias2[n], written as f16.
// 128x128 tile / 256 threads / 4 waves, BK=32, global_load_lds(16B) staging,
// 16x16x32 f16 MFMA.  (unchanged — ~40 us each)
__global__ __launch_bounds__(256)
void gemm_xproj(const _Float16* __restrict__ X,
                const _Float16* __restrict__ W,
                const float* __restrict__ bias1,
                const float* __restrict__ bias2,
                _Float16* __restrict__ out, int K) {
  __shared__ __align__(16) _Float16 As[128 * 32];
  __shared__ __align__(16) _Float16 Bs[128 * 32];
  const int tid  = threadIdx.x;
  const int wave = tid >> 6;
  const int lane = tid & 63;
  const int wr = wave >> 1, wc = wave & 1;
  const int m0 = blockIdx.x * 128, n0 = blockIdx.y * 128;
  const int fr = lane & 15;
  const int fk = (lane >> 4) * 8;
  const int cA = (lane & 3) * 8;
  const int rsub = lane >> 2;

  f32x4 acc[4][4];
#pragma unroll
  for (int a = 0; a < 4; ++a)
#pragma unroll
    for (int b = 0; b < 4; ++b)
      acc[a][b] = (f32x4){0.f, 0.f, 0.f, 0.f};

  for (int k0 = 0; k0 < K; k0 += 32) {
    __syncthreads();
#pragma unroll
    for (int q = 0; q < 2; ++q) {
      int p = wave * 2 + q;
      int r = p * 16 + rsub;
      const _Float16* gA = X + (size_t)(m0 + r) * K + (k0 + cA);
      const _Float16* gB = W + (size_t)(n0 + r) * K + (k0 + cA);
      __builtin_amdgcn_global_load_lds(
          (const __attribute__((address_space(1))) void*)gA,
          (__attribute__((address_space(3))) void*)((char*)As + p * 1024), 16, 0, 0);
      __builtin_amdgcn_global_load_lds(
          (const __attribute__((address_space(1))) void*)gB,
          (__attribute__((address_space(3))) void*)((char*)Bs + p * 1024), 16, 0, 0);
    }
    __syncthreads();

    f16x8 af[4], bfr[4];
#pragma unroll
    for (int mt = 0; mt < 4; ++mt)
      af[mt] = *(const f16x8*)&As[(wr * 64 + mt * 16 + fr) * 32 + fk];
#pragma unroll
    for (int nt = 0; nt < 4; ++nt)
      bfr[nt] = *(const f16x8*)&Bs[(wc * 64 + nt * 16 + fr) * 32 + fk];
#pragma unroll
    for (int mt = 0; mt < 4; ++mt)
#pragma unroll
      for (int nt = 0; nt < 4; ++nt)
        acc[mt][nt] = __builtin_amdgcn_mfma_f32_16x16x32_f16(af[mt], bfr[nt], acc[mt][nt], 0, 0, 0);
  }

  const int col = lane & 15, rq = lane >> 4;
#pragma unroll
  for (int nt = 0; nt < 4; ++nt) {
    int n = n0 + wc * 64 + nt * 16 + col;
    float bias = bias1[n] + bias2[n];
#pragma unroll
    for (int mt = 0; mt < 4; ++mt) {
      int mbase = m0 + wr * 64 + mt * 16 + rq * 4;
#pragma unroll
      for (int r = 0; r < 4; ++r)
        out[(size_t)(mbase + r) * H_ + n] = (_Float16)(acc[mt][nt][r] + bias);
    }
  }
}

// ---------------------------------------------------------------------------
// Recurrent scan, round-8: one WG per batch element, 1024 threads (16 waves =
// 4 waves/SIMD — r7 lesson: at 2 waves/SIMD the ~1800 cyc of memory/barrier
// stall cannot hide behind the 2048-cyc fdot2 issue floor; VALUBusy was 56%).
// Thread (r2 = tid&255, u = tid>>8) computes rows {2r2, 2r2+1} over k-quarter
// u (16 h-chunks, read as wave-broadcast b128s). W delivery per thread
// (32 slots of uint4): 4 pinned VGPR slots + 3 LDS slots (48 KB) + 25 slots
// streamed from L2 via an 8-deep ring (uniform slot base -> saddr-form loads).
// VGPR budget ~105 < 128 cap (hard requirement for a 1024-thread WG).
// seq-store issued AFTER barrier B and next-step xv prefetched at loop top:
// both drain at a barrier ~2000 cyc downstream instead of stalling this one.
__global__ __launch_bounds__(1024, 1)
void rnn_scan(const uint4* __restrict__ Wg, const _Float16* __restrict__ xproj,
              _Float16* __restrict__ seq, float* __restrict__ hlast, int mode) {
  __shared__ __align__(16) uint4 ldsW[3 * 1024];    // 48 KB (even-row slots 4..6)
  __shared__ __align__(16) _Float16 hb[2][512];     // h double buffer (2 KB)
  __shared__ __align__(16) float psum[4][512];      // k-quarter partials (8 KB)
  const int b = blockIdx.x;
  const int tid = threadIdx.x;
  const int r2 = tid & 255;                         // row pair -> rows 2r2, 2r2+1
  const int u  = tid >> 8;                          // k-quarter 0..3

  // streamed-slot consumption order: iter i uses even-slot i (i>=7) then odd
  // slot 16+i. 25 streamed slots total.
  constexpr int ORD[25] = {16, 17, 18, 19, 20, 21, 22,
                           7, 23, 8, 24, 9, 25, 10, 26, 11, 27,
                           12, 28, 13, 29, 14, 30, 15, 31};

  // pinned register slots 0..3 (even row, chunks 0..3)
  uint4 wreg[4];
#pragma unroll
  for (int i = 0; i < 4; ++i) wreg[i] = Wg[i * 1024 + tid];
#pragma unroll
  for (int i = 0; i < 4; ++i) pin4(wreg[i]);
  // LDS slots 4..6 (even row, chunks 4..6)
#pragma unroll
  for (int i = 0; i < 3; ++i) ldsW[i * 1024 + tid] = Wg[(4 + i) * 1024 + tid];

  if (tid < 512) { hb[0][tid] = (_Float16)0.f; hb[1][tid] = (_Float16)0.f; }
  __syncthreads();

  const _Float16* xp = xproj + (size_t)b * (T_ * H_) + tid;   // valid for tid<512
  _Float16* sq = seq + (size_t)b * (T_ * H_) + tid;
  float xv_cur = (tid < 512) ? (float)xp[0] : 0.f;

  int cur = 0;
  for (int t = 0; t < T_; ++t) {
    // prefetch next xv early: consumed after barrier A, drained there with slack
    int tn = (t + 1 < T_) ? (t + 1) : t;
    float xv_nxt = (tid < 512) ? (float)xp[(size_t)tn * H_] : 0.f;

    const uint4* hbu = (const uint4*)hb[cur] + u * 16;
    uint4 q[8];                                     // stream ring (32 VGPR)
#pragma unroll
    for (int p = 0; p < 8; ++p) q[p] = Wg[ORD[p] * 1024 + tid];

    float ae0 = 0.f, ae1 = 0.f, ao0 = 0.f, ao1 = 0.f;  // 4 chains
    int qi = 0;
#pragma unroll
    for (int i = 0; i < 16; ++i) {
      uint4 h = hbu[i];                             // wave-broadcast b128
      uint4 we;
      if (i < 4)      we = wreg[i];
      else if (i < 7) we = ldsW[(i - 4) * 1024 + tid];
      else {
        we = q[qi & 7];
        if (qi + 8 < 25) q[qi & 7] = Wg[ORD[qi + 8] * 1024 + tid];
        ++qi;
      }
      if (i & 1) ae1 = dot8(we, h, ae1); else ae0 = dot8(we, h, ae0);

      uint4 wo = q[qi & 7];
      if (qi + 8 < 25) q[qi & 7] = Wg[ORD[qi + 8] * 1024 + tid];
      ++qi;
      if (i & 1) ao1 = dot8(wo, h, ao1); else ao0 = dot8(wo, h, ao0);
    }
    *(f32x2*)&psum[u][2 * r2] = (f32x2){ae0 + ae1, ao0 + ao1};
    __syncthreads();                                // A: partials visible

    _Float16 h16 = (_Float16)0.f;
    float hn = 0.f;
    if (tid < 512) {
      float s = (psum[0][tid] + psum[1][tid]) + (psum[2][tid] + psum[3][tid]);
      hn = fast_tanh(s + xv_cur);
      h16 = (_Float16)hn;
      hb[cur ^ 1][tid] = h16;                       // LDS write, cheap drain at B
    }
    __syncthreads();                                // B: hb[cur^1] complete
    // global stores issued after B -> drained at next step's barrier A w/ slack
    if (tid < 512) {
      if (mode == 0) {
        sq[(size_t)t * H_] = h16;
      } else if (t == T_ - 1) {
        hlast[b * H_ + tid] = hn;
      }
    }
    xv_cur = xv_nxt;
    cur ^= 1;
  }
}

// ---------------------------------------------------------------------------
// Final FC: out[b,o] = h2[b,:] . w_fc[o,:] + b_fc[o]   (64 x 128, tiny, pure fp32)
__global__ void fc_kernel(const float* __restrict__ h2,
                          const float* __restrict__ wfc,
                          const float* __restrict__ bfc,
                          float* __restrict__ out) {
  int b = blockIdx.x, o = threadIdx.x;
  float s = bfc[o];
  const float* hv = h2 + b * H_;
  const float* wr = wfc + (size_t)o * H_;
#pragma unroll 8
  for (int k = 0; k < H_; ++k) s += hv[k] * wr[k];
  out[b * DOUT_ + o] = s;
}

// ---------------------------------------------------------------------------
extern "C" void kernel_launch(void* const* d_in, const int* in_sizes, int n_in,
                              void* d_out, int out_size, void* d_ws, size_t ws_size,
                              hipStream_t stream) {
  const float* x     = (const float*)d_in[0];
  const float* w_ih0 = (const float*)d_in[1];
  const float* w_hh0 = (const float*)d_in[2];
  const float* b_ih0 = (const float*)d_in[3];
  const float* b_hh0 = (const float*)d_in[4];
  const float* w_ih1 = (const float*)d_in[5];
  const float* w_hh1 = (const float*)d_in[6];
  const float* b_ih1 = (const float*)d_in[7];
  const float* b_hh1 = (const float*)d_in[8];
  const float* w_fc  = (const float*)d_in[9];
  const float* b_fc  = (const float*)d_in[10];

  char* ws = (char*)d_ws;
  _Float16* Ws0   = (_Float16*)(ws + 0);          // 512 KB  (w_hh0 scan layout)
  _Float16* Ws1   = (_Float16*)(ws + 524288);     // 512 KB  (w_hh1 scan layout)
  _Float16* Wih0  = (_Float16*)(ws + 1048576);    // 256 KB  (w_ih0 f16)
  _Float16* Wih1  = (_Float16*)(ws + 1310720);    // 512 KB  (w_ih1 f16)
  float*    h2    = (float*)   (ws + 2097152);    // 128 KB  (final hidden, fp32)
  _Float16* xproj = (_Float16*)(ws + 4194304);    // 32 MB   (32768x512 f16)
  _Float16* xf16  = (_Float16*)(ws + 37748736);   // x as f16, then dead...
  _Float16* h1seq = (_Float16*)(ws + 37748736);   // ...h1 sequence f16 (32 MB)

  // 1) one-shot conversions to f16
  cvt_f32_f16<<<32768, 256, 0, stream>>>(x, xf16, B_ * T_ * DIN_);
  cvt_f32_f16<<<512,   256, 0, stream>>>(w_ih0, Wih0, H_ * DIN_);
  cvt_f32_f16<<<1024,  256, 0, stream>>>(w_ih1, Wih1, H_ * H_);
  prep_w<<<256, 256, 0, stream>>>(w_hh0, w_hh1, Ws0, Ws1);

  // 2) xproj0 = x @ w_ih0^T + b_ih0 + b_hh0   (M=32768, K=256)
  gemm_xproj<<<dim3(256, 4), 256, 0, stream>>>(xf16, Wih0, b_ih0, b_hh0, xproj, DIN_);
  // 3) layer-0 scan -> h1seq
  rnn_scan<<<B_, 1024, 0, stream>>>((const uint4*)Ws0, xproj, h1seq, h2, 0);
  // 4) xproj1 = h1seq @ w_ih1^T + b_ih1 + b_hh1   (M=32768, K=512)
  gemm_xproj<<<dim3(256, 4), 256, 0, stream>>>(h1seq, Wih1, b_ih1, b_hh1, xproj, H_);
  // 5) layer-1 scan -> h2 (fp32 final hidden only)
  rnn_scan<<<B_, 1024, 0, stream>>>((const uint4*)Ws1, xproj, h1seq, h2, 1);
  // 6) FC -> d_out (fp32, 64x128)
  fc_kernel<<<B_, DOUT_, 0, stream>>>(h2, w_fc, b_fc, (float*)d_out);
}

// Round 10
// 2900.560 us; speedup vs baseline: 1.0618x; 1.0618x over previous
//
#include <hip/hip_runtime.h>

// Problem dims (fp32 in / fp32 out)
#define B_   64
#define T_   512
#define DIN_ 256
#define H_   512
#define DOUT_ 128

typedef _Float16 f16x8 __attribute__((ext_vector_type(8)));
typedef float f32x4  __attribute__((ext_vector_type(4)));
typedef _Float16 half2v __attribute__((ext_vector_type(2)));

// ---------------------------------------------------------------------------
// dot of 8 f16 pairs (w,h packed as uint4) accumulated into fp32
__device__ __forceinline__ float dot8(uint4 w, uint4 h, float s) {
#if __has_builtin(__builtin_amdgcn_fdot2)
  s = __builtin_amdgcn_fdot2(__builtin_bit_cast(half2v, w.x), __builtin_bit_cast(half2v, h.x), s, false);
  s = __builtin_amdgcn_fdot2(__builtin_bit_cast(half2v, w.y), __builtin_bit_cast(half2v, h.y), s, false);
  s = __builtin_amdgcn_fdot2(__builtin_bit_cast(half2v, w.z), __builtin_bit_cast(half2v, h.z), s, false);
  s = __builtin_amdgcn_fdot2(__builtin_bit_cast(half2v, w.w), __builtin_bit_cast(half2v, h.w), s, false);
#else
  const half2v* wp = (const half2v*)&w;
  const half2v* hp = (const half2v*)&h;
#pragma unroll
  for (int q = 0; q < 4; ++q) {
    s += (float)wp[q][0] * (float)hp[q][0] + (float)wp[q][1] * (float)hp[q][1];
  }
#endif
  return s;
}

// fast branchless tanh: tanh(x) = sign(x) * (1 - 2/(e^{2|x|}+1)); |err| ~1e-6
__device__ __forceinline__ float fast_tanh(float x) {
  float a = fabsf(x);
  float e = __expf(2.f * a);
  float r = 1.f - 2.f / (e + 1.f);
  return copysignf(r, x);
}

// opaque pin: keep v in arch VGPRs, producing loads non-rematerializable
__device__ __forceinline__ void pin4(uint4& v) {
  asm volatile("" : "+v"(v.x), "+v"(v.y), "+v"(v.z), "+v"(v.w));
}

// ---------------------------------------------------------------------------
// Generic fp32 -> f16 conversion (memory-bound, one-shot prep)
__global__ void cvt_f32_f16(const float* __restrict__ in, _Float16* __restrict__ out, int n) {
  int idx = blockIdx.x * 256 + threadIdx.x;
  if (idx < n) out[idx] = (_Float16)in[idx];
}

// ---------------------------------------------------------------------------
// Prep: W_hh (fp32 HxH) -> scan layout (identical to r7/r9):
//   chunk c = (rsub*16 + i)*512 + tid  holds  W[4*(tid&127)+rsub][(tid>>7)*128 + i*8 .. +8)
// Scan thread tid loads slot s = rsub*16+i at Wg[s*512+tid], lane-stride 16 B.
__global__ void prep_w(const float* __restrict__ w0, const float* __restrict__ w1,
                       _Float16* __restrict__ o0, _Float16* __restrict__ o1) {
  int idx = blockIdx.x * 256 + threadIdx.x;        // 0 .. 65535 (two matrices)
  const float* src = (idx < 32768) ? w0 : w1;
  _Float16* dst = (idx < 32768) ? o0 : o1;
  int c = idx & 32767;
  int tid  = c & 511;
  int rest = c >> 9;          // 0..63
  int i    = rest & 15;
  int rsub = rest >> 4;       // 0..3
  int row = 4 * (tid & 127) + rsub;
  int kc  = (tid >> 7) * 16 + i;
#pragma unroll
  for (int e = 0; e < 8; ++e)
    dst[(size_t)c * 8 + e] = (_Float16)src[row * 512 + kc * 8 + e];
}

// ---------------------------------------------------------------------------
// GEMM: out[m,n] = sum_k X[m,k]*W[n,k] + bias1[n] + bias2[n], written as f16.
// 128x128 tile / 256 threads / 4 waves, BK=32, global_load_lds(16B) staging,
// 16x16x32 f16 MFMA.  (unchanged — ~40 us each)
__global__ __launch_bounds__(256)
void gemm_xproj(const _Float16* __restrict__ X,
                const _Float16* __restrict__ W,
                const float* __restrict__ bias1,
                const float* __restrict__ bias2,
                _Float16* __restrict__ out, int K) {
  __shared__ __align__(16) _Float16 As[128 * 32];
  __shared__ __align__(16) _Float16 Bs[128 * 32];
  const int tid  = threadIdx.x;
  const int wave = tid >> 6;
  const int lane = tid & 63;
  const int wr = wave >> 1, wc = wave & 1;
  const int m0 = blockIdx.x * 128, n0 = blockIdx.y * 128;
  const int fr = lane & 15;
  const int fk = (lane >> 4) * 8;
  const int cA = (lane & 3) * 8;
  const int rsub = lane >> 2;

  f32x4 acc[4][4];
#pragma unroll
  for (int a = 0; a < 4; ++a)
#pragma unroll
    for (int b = 0; b < 4; ++b)
      acc[a][b] = (f32x4){0.f, 0.f, 0.f, 0.f};

  for (int k0 = 0; k0 < K; k0 += 32) {
    __syncthreads();
#pragma unroll
    for (int q = 0; q < 2; ++q) {
      int p = wave * 2 + q;
      int r = p * 16 + rsub;
      const _Float16* gA = X + (size_t)(m0 + r) * K + (k0 + cA);
      const _Float16* gB = W + (size_t)(n0 + r) * K + (k0 + cA);
      __builtin_amdgcn_global_load_lds(
          (const __attribute__((address_space(1))) void*)gA,
          (__attribute__((address_space(3))) void*)((char*)As + p * 1024), 16, 0, 0);
      __builtin_amdgcn_global_load_lds(
          (const __attribute__((address_space(1))) void*)gB,
          (__attribute__((address_space(3))) void*)((char*)Bs + p * 1024), 16, 0, 0);
    }
    __syncthreads();

    f16x8 af[4], bfr[4];
#pragma unroll
    for (int mt = 0; mt < 4; ++mt)
      af[mt] = *(const f16x8*)&As[(wr * 64 + mt * 16 + fr) * 32 + fk];
#pragma unroll
    for (int nt = 0; nt < 4; ++nt)
      bfr[nt] = *(const f16x8*)&Bs[(wc * 64 + nt * 16 + fr) * 32 + fk];
#pragma unroll
    for (int mt = 0; mt < 4; ++mt)
#pragma unroll
      for (int nt = 0; nt < 4; ++nt)
        acc[mt][nt] = __builtin_amdgcn_mfma_f32_16x16x32_f16(af[mt], bfr[nt], acc[mt][nt], 0, 0, 0);
  }

  const int col = lane & 15, rq = lane >> 4;
#pragma unroll
  for (int nt = 0; nt < 4; ++nt) {
    int n = n0 + wc * 64 + nt * 16 + col;
    float bias = bias1[n] + bias2[n];
#pragma unroll
    for (int mt = 0; mt < 4; ++mt) {
      int mbase = m0 + wr * 64 + mt * 16 + rq * 4;
#pragma unroll
      for (int r = 0; r < 4; ++r)
        out[(size_t)(mbase + r) * H_ + n] = (_Float16)(acc[mt][nt][r] + bias);
    }
  }
}

// ---------------------------------------------------------------------------
// Recurrent scan, round-10 = r7 skeleton (T=512, R=4 rows/thread, S=4 k-split,
// 2 waves/SIMD) with phase-correct rebalanced W delivery:
//   rows +0,+1 (slots  0..31)        -> 32 pinned uint4 (128 VGPR)
//   row  +2 chunks 0..5 (slots 32..37) -> 48 KB LDS
//   row  +2 chunks 6..7 (slots 38..39) -> 2 more pinned uint4 (8 VGPR)
//   row  +2 chunks 8..15 + row +3     -> 24 slots streamed from L2
//                                        (192 KB/step/CU, ~1800 cyc)
// r9 BUG FIX: 24 streamed slots, 24 % 8 == 0 -> the 8-deep ring returns to
// the SAME phase every step (r9 streamed 26; 26 mod 8 = 2 phase-shifted the
// ring each step -> wrong W slots from step 1 on, absmax 0.23). Refills during
// the last 8 consumptions target the next step's first slots (W is static).
// seq-store after barrier B; next xv prefetched at loop tail (drain w/ slack).
__global__ __launch_bounds__(512, 2)
void rnn_scan(const uint4* __restrict__ Wg, const _Float16* __restrict__ xproj,
              _Float16* __restrict__ seq, float* __restrict__ hlast, int mode) {
  __shared__ __align__(16) uint4 ldsW[6 * 512];     // 48 KB (slots 32..37)
  __shared__ __align__(16) _Float16 hb[2][512];     // h double buffer (2 KB)
  __shared__ __align__(16) float psum[4][512];      // k-quarter partials (8 KB)
  const int b = blockIdx.x;
  const int tid = threadIdx.x;
  const int u = tid >> 7;                           // k-quarter 0..3

  // streamed-slot consumption order per step (24 slots):
  //   i=0..7:  a3 <- row+3 chunks 0..7   (slots 48..55)
  //   i=8..15: a2 <- row+2 chunks 8..15  (slots 40..47) interleaved with
  //            a3 <- row+3 chunks 8..15  (slots 56..63)
  constexpr int C[24] = {48, 49, 50, 51, 52, 53, 54, 55,
                         40, 56, 41, 57, 42, 58, 43, 59,
                         44, 60, 45, 61, 46, 62, 47, 63};

  const uint4* WgT = Wg + tid;

  // pinned: slots 0..31 (rows +0,+1) + slots 38..39 (row+2 chunks 6..7)
  uint4 wr0[16], wr1[16], wr2a[2];
#pragma unroll
  for (int i = 0; i < 16; ++i) {
    wr0[i] = WgT[i * 512];
    wr1[i] = WgT[(16 + i) * 512];
  }
  wr2a[0] = WgT[38 * 512];
  wr2a[1] = WgT[39 * 512];
#pragma unroll
  for (int i = 0; i < 16; ++i) { pin4(wr0[i]); pin4(wr1[i]); }
  pin4(wr2a[0]); pin4(wr2a[1]);

  // LDS slots 32..37 (row +2, chunks 0..5)
#pragma unroll
  for (int i = 0; i < 6; ++i) ldsW[i * 512 + tid] = WgT[(32 + i) * 512];

  hb[0][tid] = (_Float16)0.f;
  hb[1][tid] = (_Float16)0.f;
  __syncthreads();

  const _Float16* xp = xproj + (size_t)b * (T_ * H_) + tid;
  _Float16* sq = seq + (size_t)b * (T_ * H_) + tid;

  // prefill the persistent ring with C[0..7] (steady state from step 0)
  uint4 q[8];
#pragma unroll
  for (int p = 0; p < 8; ++p) q[p] = WgT[C[p] * 512];

  int cur = 0;
  float xv = (float)xp[0];
  for (int t = 0; t < T_; ++t) {
    const uint4* hbu = (const uint4*)hb[cur] + u * 16;

    float a0 = 0.f, a1 = 0.f, a2 = 0.f, a3 = 0.f;   // 4 row chains
    int ci = 0;                                     // compile-time (full unroll)
#pragma unroll
    for (int i = 0; i < 16; ++i) {
      uint4 h = hbu[i];                             // wave-broadcast b128
      a0 = dot8(wr0[i], h, a0);
      a1 = dot8(wr1[i], h, a1);
      uint4 w2;
      if (i < 6)      w2 = ldsW[i * 512 + tid];
      else if (i < 8) w2 = wr2a[i - 6];
      else { w2 = q[ci & 7]; q[ci & 7] = WgT[C[(ci + 8) % 24] * 512]; ++ci; }
      a2 = dot8(w2, h, a2);
      uint4 w3 = q[ci & 7]; q[ci & 7] = WgT[C[(ci + 8) % 24] * 512]; ++ci;
      a3 = dot8(w3, h, a3);
    }
    // ci == 24 here; 24 % 8 == 0 -> ring phase identical for next step
    *(f32x4*)&psum[u][4 * (tid & 127)] = (f32x4){a0, a1, a2, a3};
    __syncthreads();                                // A: partials visible

    float s = (psum[0][tid] + psum[1][tid]) + (psum[2][tid] + psum[3][tid]);
    float hn = fast_tanh(s + xv);
    _Float16 h16 = (_Float16)hn;
    hb[cur ^ 1][tid] = h16;
    __syncthreads();                                // B: hb[cur^1] complete

    // global traffic after the barrier: drains at next step's barrier A
    if (mode == 0) {
      sq[(size_t)t * H_] = h16;
    } else if (t == T_ - 1) {
      hlast[b * H_ + tid] = hn;
    }
    if (t + 1 < T_) xv = (float)xp[(size_t)(t + 1) * H_];
    cur ^= 1;
  }
}

// ---------------------------------------------------------------------------
// Final FC: out[b,o] = h2[b,:] . w_fc[o,:] + b_fc[o]   (64 x 128, tiny, pure fp32)
__global__ void fc_kernel(const float* __restrict__ h2,
                          const float* __restrict__ wfc,
                          const float* __restrict__ bfc,
                          float* __restrict__ out) {
  int b = blockIdx.x, o = threadIdx.x;
  float s = bfc[o];
  const float* hv = h2 + b * H_;
  const float* wr = wfc + (size_t)o * H_;
#pragma unroll 8
  for (int k = 0; k < H_; ++k) s += hv[k] * wr[k];
  out[b * DOUT_ + o] = s;
}

// ---------------------------------------------------------------------------
extern "C" void kernel_launch(void* const* d_in, const int* in_sizes, int n_in,
                              void* d_out, int out_size, void* d_ws, size_t ws_size,
                              hipStream_t stream) {
  const float* x     = (const float*)d_in[0];
  const float* w_ih0 = (const float*)d_in[1];
  const float* w_hh0 = (const float*)d_in[2];
  const float* b_ih0 = (const float*)d_in[3];
  const float* b_hh0 = (const float*)d_in[4];
  const float* w_ih1 = (const float*)d_in[5];
  const float* w_hh1 = (const float*)d_in[6];
  const float* b_ih1 = (const float*)d_in[7];
  const float* b_hh1 = (const float*)d_in[8];
  const float* w_fc  = (const float*)d_in[9];
  const float* b_fc  = (const float*)d_in[10];

  char* ws = (char*)d_ws;
  _Float16* Ws0   = (_Float16*)(ws + 0);          // 512 KB  (w_hh0 scan layout)
  _Float16* Ws1   = (_Float16*)(ws + 524288);     // 512 KB  (w_hh1 scan layout)
  _Float16* Wih0  = (_Float16*)(ws + 1048576);    // 256 KB  (w_ih0 f16)
  _Float16* Wih1  = (_Float16*)(ws + 1310720);    // 512 KB  (w_ih1 f16)
  float*    h2    = (float*)   (ws + 2097152);    // 128 KB  (final hidden, fp32)
  _Float16* xproj = (_Float16*)(ws + 4194304);    // 32 MB   (32768x512 f16)
  _Float16* xf16  = (_Float16*)(ws + 37748736);   // x as f16, then dead...
  _Float16* h1seq = (_Float16*)(ws + 37748736);   // ...h1 sequence f16 (32 MB)

  // 1) one-shot conversions to f16
  cvt_f32_f16<<<32768, 256, 0, stream>>>(x, xf16, B_ * T_ * DIN_);
  cvt_f32_f16<<<512,   256, 0, stream>>>(w_ih0, Wih0, H_ * DIN_);
  cvt_f32_f16<<<1024,  256, 0, stream>>>(w_ih1, Wih1, H_ * H_);
  prep_w<<<256, 256, 0, stream>>>(w_hh0, w_hh1, Ws0, Ws1);

  // 2) xproj0 = x @ w_ih0^T + b_ih0 + b_hh0   (M=32768, K=256)
  gemm_xproj<<<dim3(256, 4), 256, 0, stream>>>(xf16, Wih0, b_ih0, b_hh0, xproj, DIN_);
  // 3) layer-0 scan -> h1seq
  rnn_scan<<<B_, 512, 0, stream>>>((const uint4*)Ws0, xproj, h1seq, h2, 0);
  // 4) xproj1 = h1seq @ w_ih1^T + b_ih1 + b_hh1   (M=32768, K=512)
  gemm_xproj<<<dim3(256, 4), 256, 0, stream>>>(h1seq, Wih1, b_ih1, b_hh1, xproj, H_);
  // 5) layer-1 scan -> h2 (fp32 final hidden only)
  rnn_scan<<<B_, 512, 0, stream>>>((const uint4*)Ws1, xproj, h1seq, h2, 1);
  // 6) FC -> d_out (fp32, 64x128)
  fc_kernel<<<B_, DOUT_, 0, stream>>>(h2, w_fc, b_fc, (float*)d_out);
}

// Round 11
// 2263.091 us; speedup vs baseline: 1.3609x; 1.2817x over previous
//
#include <hip/hip_runtime.h>

// Problem dims (fp32 in / fp32 out)
#define B_   64
#define T_   512
#define DIN_ 256
#define H_   512
#define DOUT_ 128

typedef _Float16 f16x8 __attribute__((ext_vector_type(8)));
typedef float f32x4  __attribute__((ext_vector_type(4)));
typedef _Float16 half2v __attribute__((ext_vector_type(2)));

// ---------------------------------------------------------------------------
// dot of 8 f16 pairs (w,h packed as uint4) accumulated into fp32
__device__ __forceinline__ float dot8(uint4 w, uint4 h, float s) {
#if __has_builtin(__builtin_amdgcn_fdot2)
  s = __builtin_amdgcn_fdot2(__builtin_bit_cast(half2v, w.x), __builtin_bit_cast(half2v, h.x), s, false);
  s = __builtin_amdgcn_fdot2(__builtin_bit_cast(half2v, w.y), __builtin_bit_cast(half2v, h.y), s, false);
  s = __builtin_amdgcn_fdot2(__builtin_bit_cast(half2v, w.z), __builtin_bit_cast(half2v, h.z), s, false);
  s = __builtin_amdgcn_fdot2(__builtin_bit_cast(half2v, w.w), __builtin_bit_cast(half2v, h.w), s, false);
#else
  const half2v* wp = (const half2v*)&w;
  const half2v* hp = (const half2v*)&h;
#pragma unroll
  for (int q = 0; q < 4; ++q) {
    s += (float)wp[q][0] * (float)hp[q][0] + (float)wp[q][1] * (float)hp[q][1];
  }
#endif
  return s;
}

// fast branchless tanh: tanh(x) = sign(x) * (1 - 2/(e^{2|x|}+1)); |err| ~1e-6
__device__ __forceinline__ float fast_tanh(float x) {
  float a = fabsf(x);
  float e = __expf(2.f * a);
  float r = 1.f - 2.f / (e + 1.f);
  return copysignf(r, x);
}

// opaque pin: keep v in arch VGPRs, producing loads non-rematerializable
__device__ __forceinline__ void pin4(uint4& v) {
  asm volatile("" : "+v"(v.x), "+v"(v.y), "+v"(v.z), "+v"(v.w));
}

// ---------------------------------------------------------------------------
// Generic fp32 -> f16 conversion (memory-bound, one-shot prep)
__global__ void cvt_f32_f16(const float* __restrict__ in, _Float16* __restrict__ out, int n) {
  int idx = blockIdx.x * 256 + threadIdx.x;
  if (idx < n) out[idx] = (_Float16)in[idx];
}

// ---------------------------------------------------------------------------
// Prep: W_hh (fp32 HxH) -> round-11 scan layout (R=8 rows/thread, S=8 k-split):
//   slot s = r8*8 + i (r8 = row-sub 0..7, i = chunk within k-eighth 0..7)
//   chunk c = s*512 + tid  holds  W[8*(tid&63)+r8][((tid>>6)*8 + i)*8 .. +8)
// Scan thread tid loads slot s at Wg[s*512+tid], lane-stride 16 B (coalesced).
__global__ void prep_w(const float* __restrict__ w0, const float* __restrict__ w1,
                       _Float16* __restrict__ o0, _Float16* __restrict__ o1) {
  int idx = blockIdx.x * 256 + threadIdx.x;        // 0 .. 65535 (two matrices)
  const float* src = (idx < 32768) ? w0 : w1;
  _Float16* dst = (idx < 32768) ? o0 : o1;
  int c = idx & 32767;
  int tid = c & 511;
  int s   = c >> 9;           // 0..63
  int r8  = s >> 3;
  int i   = s & 7;
  int row = 8 * (tid & 63) + r8;
  int kc  = (tid >> 6) * 8 + i;
#pragma unroll
  for (int e = 0; e < 8; ++e)
    dst[(size_t)c * 8 + e] = (_Float16)src[row * 512 + kc * 8 + e];
}

// ---------------------------------------------------------------------------
// GEMM: out[m,n] = sum_k X[m,k]*W[n,k] + bias1[n] + bias2[n], written as f16.
// 128x128 tile / 256 threads / 4 waves, BK=32, global_load_lds(16B) staging,
// 16x16x32 f16 MFMA.  (unchanged — ~40 us each)
__global__ __launch_bounds__(256)
void gemm_xproj(const _Float16* __restrict__ X,
                const _Float16* __restrict__ W,
                const float* __restrict__ bias1,
                const float* __restrict__ bias2,
                _Float16* __restrict__ out, int K) {
  __shared__ __align__(16) _Float16 As[128 * 32];
  __shared__ __align__(16) _Float16 Bs[128 * 32];
  const int tid  = threadIdx.x;
  const int wave = tid >> 6;
  const int lane = tid & 63;
  const int wr = wave >> 1, wc = wave & 1;
  const int m0 = blockIdx.x * 128, n0 = blockIdx.y * 128;
  const int fr = lane & 15;
  const int fk = (lane >> 4) * 8;
  const int cA = (lane & 3) * 8;
  const int rsub = lane >> 2;

  f32x4 acc[4][4];
#pragma unroll
  for (int a = 0; a < 4; ++a)
#pragma unroll
    for (int b = 0; b < 4; ++b)
      acc[a][b] = (f32x4){0.f, 0.f, 0.f, 0.f};

  for (int k0 = 0; k0 < K; k0 += 32) {
    __syncthreads();
#pragma unroll
    for (int q = 0; q < 2; ++q) {
      int p = wave * 2 + q;
      int r = p * 16 + rsub;
      const _Float16* gA = X + (size_t)(m0 + r) * K + (k0 + cA);
      const _Float16* gB = W + (size_t)(n0 + r) * K + (k0 + cA);
      __builtin_amdgcn_global_load_lds(
          (const __attribute__((address_space(1))) void*)gA,
          (__attribute__((address_space(3))) void*)((char*)As + p * 1024), 16, 0, 0);
      __builtin_amdgcn_global_load_lds(
          (const __attribute__((address_space(1))) void*)gB,
          (__attribute__((address_space(3))) void*)((char*)Bs + p * 1024), 16, 0, 0);
    }
    __syncthreads();

    f16x8 af[4], bfr[4];
#pragma unroll
    for (int mt = 0; mt < 4; ++mt)
      af[mt] = *(const f16x8*)&As[(wr * 64 + mt * 16 + fr) * 32 + fk];
#pragma unroll
    for (int nt = 0; nt < 4; ++nt)
      bfr[nt] = *(const f16x8*)&Bs[(wc * 64 + nt * 16 + fr) * 32 + fk];
#pragma unroll
    for (int mt = 0; mt < 4; ++mt)
#pragma unroll
      for (int nt = 0; nt < 4; ++nt)
        acc[mt][nt] = __builtin_amdgcn_mfma_f32_16x16x32_f16(af[mt], bfr[nt], acc[mt][nt], 0, 0, 0);
  }

  const int col = lane & 15, rq = lane >> 4;
#pragma unroll
  for (int nt = 0; nt < 4; ++nt) {
    int n = n0 + wc * 64 + nt * 16 + col;
    float bias = bias1[n] + bias2[n];
#pragma unroll
    for (int mt = 0; mt < 4; ++mt) {
      int mbase = m0 + wr * 64 + mt * 16 + rq * 4;
#pragma unroll
      for (int r = 0; r < 4; ++r)
        out[(size_t)(mbase + r) * H_ + n] = (_Float16)(acc[mt][nt][r] + bias);
    }
  }
}

// ---------------------------------------------------------------------------
// Recurrent scan, round-11: R=8 rows/thread, S=8 k-split, 512 threads,
// 2 waves/SIMD. Thread (g=tid&63, p=tid>>6) computes rows {8g..8g+7} over
// k-eighth p (wave == k-part -> h reads stay wave-broadcast). This cuts the
// r3-wall LDS h-broadcast from 6144/R: R=4 gave 1536 cyc (r7), R=8 gives 768.
// W delivery (r4/r6/r10 lesson: >16 pinned uint4/thread get demoted — cap it):
//   slots  0..15 (rows +0,+1)        -> 16 pinned uint4 = 64 VGPR
//   slots 16..21 (row +2, chunks0..5) -> 48 KB LDS
//   42 remaining slots               -> streamed from L2 (344 KB/step/CU)
// 14-deep persistent ring (42 = 3*14 -> phase-correct every step; prefetch
// distance ~2.3 dot-iterations ~ L2 latency). psum in f16 (8 KB; fits the
// 64 KB static-LDS budget; adds ~1e-3 abs error, 6x headroom available).
// seq store after barrier B; next xv prefetched late (drain with slack).
__global__ __launch_bounds__(512, 2)
void rnn_scan(const uint4* __restrict__ Wg, const _Float16* __restrict__ xproj,
              _Float16* __restrict__ seq, float* __restrict__ hlast, int mode) {
  __shared__ __align__(16) uint4 ldsW[6 * 512];     // 48 KB (slots 16..21)
  __shared__ __align__(16) _Float16 hb[2][512];     // h double buffer (2 KB)
  __shared__ __align__(16) _Float16 psum[8][512];   // k-part partials, f16 (8 KB)
  const int b = blockIdx.x;
  const int tid = threadIdx.x;
  const int g = tid & 63;                           // row-group: rows 8g..8g+7
  const int p = tid >> 6;                           // k-eighth == wave index

  // streamed-slot consumption order (slot = r8*8+i):
  //  i=0..5: rows 3..7 (row2 chunk comes from LDS);  i=6,7: rows 2..7
  constexpr int C[42] = {
    24, 32, 40, 48, 56,
    25, 33, 41, 49, 57,
    26, 34, 42, 50, 58,
    27, 35, 43, 51, 59,
    28, 36, 44, 52, 60,
    29, 37, 45, 53, 61,
    22, 30, 38, 46, 54, 62,
    23, 31, 39, 47, 55, 63};

  const uint4* WgT = Wg + tid;

  // pinned slots 0..15 (rows +0,+1): 64 VGPR — at the proven ceiling
  uint4 wreg[16];
#pragma unroll
  for (int i = 0; i < 16; ++i) wreg[i] = WgT[i * 512];
#pragma unroll
  for (int i = 0; i < 16; ++i) pin4(wreg[i]);

  // LDS slots 16..21 (row +2, chunks 0..5)
#pragma unroll
  for (int i = 0; i < 6; ++i) ldsW[i * 512 + tid] = WgT[(16 + i) * 512];

  hb[0][tid] = (_Float16)0.f;
  hb[1][tid] = (_Float16)0.f;
  __syncthreads();

  const _Float16* xp = xproj + (size_t)b * (T_ * H_) + tid;
  _Float16* sq = seq + (size_t)b * (T_ * H_) + tid;

  // persistent 14-deep ring, prefilled with C[0..13]
  uint4 q[14];
#pragma unroll
  for (int j = 0; j < 14; ++j) q[j] = WgT[C[j] * 512];

  int cur = 0;
  float xv = (float)xp[0];
  for (int t = 0; t < T_; ++t) {
    const uint4* hbu = (const uint4*)hb[cur] + p * 8;

    float a[8];
#pragma unroll
    for (int r = 0; r < 8; ++r) a[r] = 0.f;

    int ci = 0;                                     // compile-time (full unroll)
#pragma unroll
    for (int i = 0; i < 8; ++i) {
      uint4 h = hbu[i];                             // wave-broadcast b128
      a[0] = dot8(wreg[i], h, a[0]);
      a[1] = dot8(wreg[8 + i], h, a[1]);
      uint4 w2;
      if (i < 6) {
        w2 = ldsW[i * 512 + tid];
      } else {
        w2 = q[ci % 14]; q[ci % 14] = WgT[C[(ci + 14) % 42] * 512]; ++ci;
      }
      a[2] = dot8(w2, h, a[2]);
#pragma unroll
      for (int r = 3; r < 8; ++r) {
        uint4 wv = q[ci % 14]; q[ci % 14] = WgT[C[(ci + 14) % 42] * 512]; ++ci;
        a[r] = dot8(wv, h, a[r]);
      }
    }
    // ci == 42; 42 % 14 == 0 -> ring phase identical next step.
    // psum write: 8 f16 = one b128 at lane-stride 16 B -> conflict-free
    f16x8 pk;
#pragma unroll
    for (int r = 0; r < 8; ++r) pk[r] = (_Float16)a[r];
    *(f16x8*)&psum[p][8 * g] = pk;
    __syncthreads();                                // A: partials visible

    float s = 0.f;
#pragma unroll
    for (int pp = 0; pp < 8; ++pp) s += (float)psum[pp][tid];
    float hn = fast_tanh(s + xv);
    _Float16 h16 = (_Float16)hn;
    hb[cur ^ 1][tid] = h16;
    __syncthreads();                                // B: hb[cur^1] complete

    // global traffic after the barrier: drains at next step's barrier A
    if (mode == 0) {
      sq[(size_t)t * H_] = h16;
    } else if (t == T_ - 1) {
      hlast[b * H_ + tid] = hn;
    }
    if (t + 1 < T_) xv = (float)xp[(size_t)(t + 1) * H_];
    cur ^= 1;
  }
}

// ---------------------------------------------------------------------------
// Final FC: out[b,o] = h2[b,:] . w_fc[o,:] + b_fc[o]   (64 x 128, tiny, pure fp32)
__global__ void fc_kernel(const float* __restrict__ h2,
                          const float* __restrict__ wfc,
                          const float* __restrict__ bfc,
                          float* __restrict__ out) {
  int b = blockIdx.x, o = threadIdx.x;
  float s = bfc[o];
  const float* hv = h2 + b * H_;
  const float* wr = wfc + (size_t)o * H_;
#pragma unroll 8
  for (int k = 0; k < H_; ++k) s += hv[k] * wr[k];
  out[b * DOUT_ + o] = s;
}

// ---------------------------------------------------------------------------
extern "C" void kernel_launch(void* const* d_in, const int* in_sizes, int n_in,
                              void* d_out, int out_size, void* d_ws, size_t ws_size,
                              hipStream_t stream) {
  const float* x     = (const float*)d_in[0];
  const float* w_ih0 = (const float*)d_in[1];
  const float* w_hh0 = (const float*)d_in[2];
  const float* b_ih0 = (const float*)d_in[3];
  const float* b_hh0 = (const float*)d_in[4];
  const float* w_ih1 = (const float*)d_in[5];
  const float* w_hh1 = (const float*)d_in[6];
  const float* b_ih1 = (const float*)d_in[7];
  const float* b_hh1 = (const float*)d_in[8];
  const float* w_fc  = (const float*)d_in[9];
  const float* b_fc  = (const float*)d_in[10];

  char* ws = (char*)d_ws;
  _Float16* Ws0   = (_Float16*)(ws + 0);          // 512 KB  (w_hh0 scan layout)
  _Float16* Ws1   = (_Float16*)(ws + 524288);     // 512 KB  (w_hh1 scan layout)
  _Float16* Wih0  = (_Float16*)(ws + 1048576);    // 256 KB  (w_ih0 f16)
  _Float16* Wih1  = (_Float16*)(ws + 1310720);    // 512 KB  (w_ih1 f16)
  float*    h2    = (float*)   (ws + 2097152);    // 128 KB  (final hidden, fp32)
  _Float16* xproj = (_Float16*)(ws + 4194304);    // 32 MB   (32768x512 f16)
  _Float16* xf16  = (_Float16*)(ws + 37748736);   // x as f16, then dead...
  _Float16* h1seq = (_Float16*)(ws + 37748736);   // ...h1 sequence f16 (32 MB)

  // 1) one-shot conversions to f16
  cvt_f32_f16<<<32768, 256, 0, stream>>>(x, xf16, B_ * T_ * DIN_);
  cvt_f32_f16<<<512,   256, 0, stream>>>(w_ih0, Wih0, H_ * DIN_);
  cvt_f32_f16<<<1024,  256, 0, stream>>>(w_ih1, Wih1, H_ * H_);
  prep_w<<<256, 256, 0, stream>>>(w_hh0, w_hh1, Ws0, Ws1);

  // 2) xproj0 = x @ w_ih0^T + b_ih0 + b_hh0   (M=32768, K=256)
  gemm_xproj<<<dim3(256, 4), 256, 0, stream>>>(xf16, Wih0, b_ih0, b_hh0, xproj, DIN_);
  // 3) layer-0 scan -> h1seq
  rnn_scan<<<B_, 512, 0, stream>>>((const uint4*)Ws0, xproj, h1seq, h2, 0);
  // 4) xproj1 = h1seq @ w_ih1^T + b_ih1 + b_hh1   (M=32768, K=512)
  gemm_xproj<<<dim3(256, 4), 256, 0, stream>>>(h1seq, Wih1, b_ih1, b_hh1, xproj, H_);
  // 5) layer-1 scan -> h2 (fp32 final hidden only)
  rnn_scan<<<B_, 512, 0, stream>>>((const uint4*)Ws1, xproj, h1seq, h2, 1);
  // 6) FC -> d_out (fp32, 64x128)
  fc_kernel<<<B_, DOUT_, 0, stream>>>(h2, w_fc, b_fc, (float*)d_out);
}

// Round 12
// 2007.332 us; speedup vs baseline: 1.5343x; 1.1274x over previous
//
#include <hip/hip_runtime.h>

// Problem dims (fp32 in / fp32 out)
#define B_   64
#define T_   512
#define DIN_ 256
#define H_   512
#define DOUT_ 128

typedef _Float16 f16x8 __attribute__((ext_vector_type(8)));
typedef float f32x4  __attribute__((ext_vector_type(4)));
typedef _Float16 half2v __attribute__((ext_vector_type(2)));

// ---------------------------------------------------------------------------
// dot of 8 f16 pairs (w,h packed as uint4) accumulated into fp32
__device__ __forceinline__ float dot8(uint4 w, uint4 h, float s) {
#if __has_builtin(__builtin_amdgcn_fdot2)
  s = __builtin_amdgcn_fdot2(__builtin_bit_cast(half2v, w.x), __builtin_bit_cast(half2v, h.x), s, false);
  s = __builtin_amdgcn_fdot2(__builtin_bit_cast(half2v, w.y), __builtin_bit_cast(half2v, h.y), s, false);
  s = __builtin_amdgcn_fdot2(__builtin_bit_cast(half2v, w.z), __builtin_bit_cast(half2v, h.z), s, false);
  s = __builtin_amdgcn_fdot2(__builtin_bit_cast(half2v, w.w), __builtin_bit_cast(half2v, h.w), s, false);
#else
  const half2v* wp = (const half2v*)&w;
  const half2v* hp = (const half2v*)&h;
#pragma unroll
  for (int q = 0; q < 4; ++q) {
    s += (float)wp[q][0] * (float)hp[q][0] + (float)wp[q][1] * (float)hp[q][1];
  }
#endif
  return s;
}

// fast branchless tanh: tanh(x) = sign(x) * (1 - 2/(e^{2|x|}+1)); |err| ~1e-6
__device__ __forceinline__ float fast_tanh(float x) {
  float a = fabsf(x);
  float e = __expf(2.f * a);
  float r = 1.f - 2.f / (e + 1.f);
  return copysignf(r, x);
}

// opaque pin: keep v in arch VGPRs, producing loads non-rematerializable
__device__ __forceinline__ void pin4(uint4& v) {
  asm volatile("" : "+v"(v.x), "+v"(v.y), "+v"(v.z), "+v"(v.w));
}

// ---------------------------------------------------------------------------
// Generic fp32 -> f16 conversion (memory-bound, one-shot prep)
__global__ void cvt_f32_f16(const float* __restrict__ in, _Float16* __restrict__ out, int n) {
  int idx = blockIdx.x * 256 + threadIdx.x;
  if (idx < n) out[idx] = (_Float16)in[idx];
}

// ---------------------------------------------------------------------------
// Prep: W_hh (fp32 HxH) -> scan layout (identical to r7):
//   chunk c = (rsub*16 + i)*512 + tid  holds  W[4*(tid&127)+rsub][(tid>>7)*128 + i*8 .. +8)
// Scan thread tid loads slot s = rsub*16+i at Wg[s*512+tid], lane-stride 16 B.
__global__ void prep_w(const float* __restrict__ w0, const float* __restrict__ w1,
                       _Float16* __restrict__ o0, _Float16* __restrict__ o1) {
  int idx = blockIdx.x * 256 + threadIdx.x;        // 0 .. 65535 (two matrices)
  const float* src = (idx < 32768) ? w0 : w1;
  _Float16* dst = (idx < 32768) ? o0 : o1;
  int c = idx & 32767;
  int tid  = c & 511;
  int rest = c >> 9;          // 0..63
  int i    = rest & 15;
  int rsub = rest >> 4;       // 0..3
  int row = 4 * (tid & 127) + rsub;
  int kc  = (tid >> 7) * 16 + i;
#pragma unroll
  for (int e = 0; e < 8; ++e)
    dst[(size_t)c * 8 + e] = (_Float16)src[row * 512 + kc * 8 + e];
}

// ---------------------------------------------------------------------------
// GEMM: out[m,n] = sum_k X[m,k]*W[n,k] + bias1[n] + bias2[n], written as f16.
// 128x128 tile / 256 threads / 4 waves, BK=32, global_load_lds(16B) staging,
// 16x16x32 f16 MFMA.  (unchanged — ~40 us each)
__global__ __launch_bounds__(256)
void gemm_xproj(const _Float16* __restrict__ X,
                const _Float16* __restrict__ W,
                const float* __restrict__ bias1,
                const float* __restrict__ bias2,
                _Float16* __restrict__ out, int K) {
  __shared__ __align__(16) _Float16 As[128 * 32];
  __shared__ __align__(16) _Float16 Bs[128 * 32];
  const int tid  = threadIdx.x;
  const int wave = tid >> 6;
  const int lane = tid & 63;
  const int wr = wave >> 1, wc = wave & 1;
  const int m0 = blockIdx.x * 128, n0 = blockIdx.y * 128;
  const int fr = lane & 15;
  const int fk = (lane >> 4) * 8;
  const int cA = (lane & 3) * 8;
  const int rsub = lane >> 2;

  f32x4 acc[4][4];
#pragma unroll
  for (int a = 0; a < 4; ++a)
#pragma unroll
    for (int b = 0; b < 4; ++b)
      acc[a][b] = (f32x4){0.f, 0.f, 0.f, 0.f};

  for (int k0 = 0; k0 < K; k0 += 32) {
    __syncthreads();
#pragma unroll
    for (int q = 0; q < 2; ++q) {
      int p = wave * 2 + q;
      int r = p * 16 + rsub;
      const _Float16* gA = X + (size_t)(m0 + r) * K + (k0 + cA);
      const _Float16* gB = W + (size_t)(n0 + r) * K + (k0 + cA);
      __builtin_amdgcn_global_load_lds(
          (const __attribute__((address_space(1))) void*)gA,
          (__attribute__((address_space(3))) void*)((char*)As + p * 1024), 16, 0, 0);
      __builtin_amdgcn_global_load_lds(
          (const __attribute__((address_space(1))) void*)gB,
          (__attribute__((address_space(3))) void*)((char*)Bs + p * 1024), 16, 0, 0);
    }
    __syncthreads();

    f16x8 af[4], bfr[4];
#pragma unroll
    for (int mt = 0; mt < 4; ++mt)
      af[mt] = *(const f16x8*)&As[(wr * 64 + mt * 16 + fr) * 32 + fk];
#pragma unroll
    for (int nt = 0; nt < 4; ++nt)
      bfr[nt] = *(const f16x8*)&Bs[(wc * 64 + nt * 16 + fr) * 32 + fk];
#pragma unroll
    for (int mt = 0; mt < 4; ++mt)
#pragma unroll
      for (int nt = 0; nt < 4; ++nt)
        acc[mt][nt] = __builtin_amdgcn_mfma_f32_16x16x32_f16(af[mt], bfr[nt], acc[mt][nt], 0, 0, 0);
  }

  const int col = lane & 15, rq = lane >> 4;
#pragma unroll
  for (int nt = 0; nt < 4; ++nt) {
    int n = n0 + wc * 64 + nt * 16 + col;
    float bias = bias1[n] + bias2[n];
#pragma unroll
    for (int mt = 0; mt < 4; ++mt) {
      int mbase = m0 + wr * 64 + mt * 16 + rq * 4;
#pragma unroll
      for (int r = 0; r < 4; ++r)
        out[(size_t)(mbase + r) * H_ + n] = (_Float16)(acc[mt][nt][r] + bias);
    }
  }
}

// ---------------------------------------------------------------------------
// Recurrent scan, round-12 = r7 skeleton (T=512, R=4 rows/thread, S=4 k-split,
// 512 threads, 2 waves/SIMD) with the streamed-W pole shaved via DYNAMIC LDS:
//   row +0 (slots  0..15) -> 16 pinned uint4 = 64 VGPR  (proven ceiling;
//                            r10/r11: anything beyond ~24 live uint4 demotes
//                            at the compiler's hard 128-VGPR cap for 512-thr)
//   row +1 (slots 16..31) -> 128 KB DYNAMIC LDS (1 WG/CU, 160 KB available;
//                            static cap of 64 KB was the only reason r7
//                            streamed this row)
//   rows +2,+3 (slots 32..63) -> 32 slots streamed from L2: 256 KB/step/CU
//                            (down from r7's 344 KB — stream measured at
//                            ~128 B/cyc/CU was r7's pole: 2700 -> ~2000 cyc)
// 8-deep persistent ring, 32 % 8 == 0 -> phase-correct each step (r9 lesson).
// Predicted step: max(VALU 2350, stream 2000, LDS ~1500) ~ 2600-3000 cyc.
__global__ __launch_bounds__(512, 2)
void rnn_scan(const uint4* __restrict__ Wg, const _Float16* __restrict__ xproj,
              _Float16* __restrict__ seq, float* __restrict__ hlast, int mode) {
  extern __shared__ __align__(16) uint4 ldsW[];     // 16*512 uint4 = 128 KB dynamic
  __shared__ __align__(16) _Float16 hb[2][512];     // h double buffer (2 KB)
  __shared__ __align__(16) float psum[4][512];      // k-quarter partials (8 KB)
  const int b = blockIdx.x;
  const int tid = threadIdx.x;
  const int u = tid >> 7;                           // k-quarter 0..3

  // streamed-slot consumption order: per chunk i, slot 32+i (row+2) then 48+i
  // (row+3). 32 entries; ring depth 8; 32 % 8 == 0 -> steady-state phase.
  constexpr int C[32] = {32, 48, 33, 49, 34, 50, 35, 51,
                         36, 52, 37, 53, 38, 54, 39, 55,
                         40, 56, 41, 57, 42, 58, 43, 59,
                         44, 60, 45, 61, 46, 62, 47, 63};

  const uint4* WgT = Wg + tid;

  // pinned slots 0..15 (row +0): 64 VGPR — at the proven ceiling
  uint4 wreg[16];
#pragma unroll
  for (int i = 0; i < 16; ++i) wreg[i] = WgT[i * 512];
#pragma unroll
  for (int i = 0; i < 16; ++i) pin4(wreg[i]);

  // dynamic-LDS slots 16..31 (row +1, all 16 chunks): 128 KB
#pragma unroll
  for (int i = 0; i < 16; ++i) ldsW[i * 512 + tid] = WgT[(16 + i) * 512];

  hb[0][tid] = (_Float16)0.f;
  hb[1][tid] = (_Float16)0.f;
  __syncthreads();

  const _Float16* xp = xproj + (size_t)b * (T_ * H_) + tid;
  _Float16* sq = seq + (size_t)b * (T_ * H_) + tid;

  // prefill the persistent 8-deep ring with C[0..7]
  uint4 q[8];
#pragma unroll
  for (int p = 0; p < 8; ++p) q[p] = WgT[C[p] * 512];

  int cur = 0;
  float xv = (float)xp[0];
  for (int t = 0; t < T_; ++t) {
    const uint4* hbu = (const uint4*)hb[cur] + u * 16;

    float a0 = 0.f, a1 = 0.f, a2 = 0.f, a3 = 0.f;   // 4 row chains
    int ci = 0;                                     // compile-time (full unroll)
#pragma unroll
    for (int i = 0; i < 16; ++i) {
      uint4 h = hbu[i];                             // wave-uniform b128 (broadcast)
      a0 = dot8(wreg[i], h, a0);
      a1 = dot8(ldsW[i * 512 + tid], h, a1);
      uint4 w2 = q[ci & 7]; q[ci & 7] = WgT[C[(ci + 8) & 31] * 512]; ++ci;
      a2 = dot8(w2, h, a2);
      uint4 w3 = q[ci & 7]; q[ci & 7] = WgT[C[(ci + 8) & 31] * 512]; ++ci;
      a3 = dot8(w3, h, a3);
    }
    // ci == 32; 32 % 8 == 0 -> ring phase identical next step.
    // one contiguous b128 per thread, conflict-free
    *(f32x4*)&psum[u][4 * (tid & 127)] = (f32x4){a0, a1, a2, a3};
    __syncthreads();                                // A: partials visible

    float s = (psum[0][tid] + psum[1][tid]) + (psum[2][tid] + psum[3][tid]);
    float hn = fast_tanh(s + xv);
    _Float16 h16 = (_Float16)hn;
    hb[cur ^ 1][tid] = h16;
    __syncthreads();                                // B: hb[cur^1] complete

    // global traffic after the barrier: drains at next step's barrier A
    if (mode == 0) {
      sq[(size_t)t * H_] = h16;
    } else if (t == T_ - 1) {
      hlast[b * H_ + tid] = hn;
    }
    if (t + 1 < T_) xv = (float)xp[(size_t)(t + 1) * H_];
    cur ^= 1;
  }
}

// ---------------------------------------------------------------------------
// Final FC: out[b,o] = h2[b,:] . w_fc[o,:] + b_fc[o]   (64 x 128, tiny, pure fp32)
__global__ void fc_kernel(const float* __restrict__ h2,
                          const float* __restrict__ wfc,
                          const float* __restrict__ bfc,
                          float* __restrict__ out) {
  int b = blockIdx.x, o = threadIdx.x;
  float s = bfc[o];
  const float* hv = h2 + b * H_;
  const float* wr = wfc + (size_t)o * H_;
#pragma unroll 8
  for (int k = 0; k < H_; ++k) s += hv[k] * wr[k];
  out[b * DOUT_ + o] = s;
}

// ---------------------------------------------------------------------------
extern "C" void kernel_launch(void* const* d_in, const int* in_sizes, int n_in,
                              void* d_out, int out_size, void* d_ws, size_t ws_size,
                              hipStream_t stream) {
  const float* x     = (const float*)d_in[0];
  const float* w_ih0 = (const float*)d_in[1];
  const float* w_hh0 = (const float*)d_in[2];
  const float* b_ih0 = (const float*)d_in[3];
  const float* b_hh0 = (const float*)d_in[4];
  const float* w_ih1 = (const float*)d_in[5];
  const float* w_hh1 = (const float*)d_in[6];
  const float* b_ih1 = (const float*)d_in[7];
  const float* b_hh1 = (const float*)d_in[8];
  const float* w_fc  = (const float*)d_in[9];
  const float* b_fc  = (const float*)d_in[10];

  // allow 128 KB dynamic LDS on the scan (idempotent host call; not a stream
  // op, graph-capture-safe; no static guard per harness rules)
  (void)hipFuncSetAttribute((const void*)rnn_scan,
                            hipFuncAttributeMaxDynamicSharedMemorySize,
                            16 * 512 * 16 /* 131072 */);

  char* ws = (char*)d_ws;
  _Float16* Ws0   = (_Float16*)(ws + 0);          // 512 KB  (w_hh0 scan layout)
  _Float16* Ws1   = (_Float16*)(ws + 524288);     // 512 KB  (w_hh1 scan layout)
  _Float16* Wih0  = (_Float16*)(ws + 1048576);    // 256 KB  (w_ih0 f16)
  _Float16* Wih1  = (_Float16*)(ws + 1310720);    // 512 KB  (w_ih1 f16)
  float*    h2    = (float*)   (ws + 2097152);    // 128 KB  (final hidden, fp32)
  _Float16* xproj = (_Float16*)(ws + 4194304);    // 32 MB   (32768x512 f16)
  _Float16* xf16  = (_Float16*)(ws + 37748736);   // x as f16, then dead...
  _Float16* h1seq = (_Float16*)(ws + 37748736);   // ...h1 sequence f16 (32 MB)

  // 1) one-shot conversions to f16
  cvt_f32_f16<<<32768, 256, 0, stream>>>(x, xf16, B_ * T_ * DIN_);
  cvt_f32_f16<<<512,   256, 0, stream>>>(w_ih0, Wih0, H_ * DIN_);
  cvt_f32_f16<<<1024,  256, 0, stream>>>(w_ih1, Wih1, H_ * H_);
  prep_w<<<256, 256, 0, stream>>>(w_hh0, w_hh1, Ws0, Ws1);

  // 2) xproj0 = x @ w_ih0^T + b_ih0 + b_hh0   (M=32768, K=256)
  gemm_xproj<<<dim3(256, 4), 256, 0, stream>>>(xf16, Wih0, b_ih0, b_hh0, xproj, DIN_);
  // 3) layer-0 scan -> h1seq   (128 KB dynamic LDS)
  rnn_scan<<<B_, 512, 131072, stream>>>((const uint4*)Ws0, xproj, h1seq, h2, 0);
  // 4) xproj1 = h1seq @ w_ih1^T + b_ih1 + b_hh1   (M=32768, K=512)
  gemm_xproj<<<dim3(256, 4), 256, 0, stream>>>(h1seq, Wih1, b_ih1, b_hh1, xproj, H_);
  // 5) layer-1 scan -> h2 (fp32 final hidden only)
  rnn_scan<<<B_, 512, 131072, stream>>>((const uint4*)Ws1, xproj, h1seq, h2, 1);
  // 6) FC -> d_out (fp32, 64x128)
  fc_kernel<<<B_, DOUT_, 0, stream>>>(h2, w_fc, b_fc, (float*)d_out);
}